// Round 1
// baseline (484.381 us; speedup 1.0000x reference)
//
#include <hip/hip_runtime.h>

#define U_    128
#define DIN   10240
#define RANK  320
#define NS    32

// -------------------------------------------------------------------------
// Kernel 1: split-K projections with atomic accumulate.
//   t[128,320] = x @ W_delta     (blocks 0..799:   5 n-tiles x 8 u-tiles x 20 k-chunks)
//   B[128,32]  = x @ W_B         (blocks 800..959: 8 u-tiles x 20 k-chunks)
//   C[128,32]  = x @ W_C         (blocks 960..1119)
// One wave per block; lane = output column n. k is a pure loop/block index
// => x[(u0+i)*DIN + k] is wave-uniform => compiler emits s_load (scalar path),
// inner loop is v_fmac_f32 vgpr,sgpr,vgpr — no LDS needed.
// -------------------------------------------------------------------------
__global__ __launch_bounds__(64) void proj_kernel(
    const float* __restrict__ x,
    const float* __restrict__ Wd, const float* __restrict__ Wb,
    const float* __restrict__ Wc,
    float* __restrict__ t_out, float* __restrict__ B_out, float* __restrict__ C_out)
{
    int b = blockIdx.x;
    const float* W; float* out; int ldw, ncols, n0, u0, k0;
    if (b < 800) {
        int nt = b % 5; int ut = (b / 5) % 8; int kc = b / 40;
        W = Wd; out = t_out; ldw = RANK; ncols = RANK;
        n0 = nt * 64; u0 = ut * 16; k0 = kc * 512;
    } else if (b < 960) {
        int b2 = b - 800; int ut = b2 % 8; int kc = b2 / 8;
        W = Wb; out = B_out; ldw = NS; ncols = NS;
        n0 = 0; u0 = ut * 16; k0 = kc * 512;
    } else {
        int b2 = b - 960; int ut = b2 % 8; int kc = b2 / 8;
        W = Wc; out = C_out; ldw = NS; ncols = NS;
        n0 = 0; u0 = ut * 16; k0 = kc * 512;
    }
    int lane = threadIdx.x;
    int n = n0 + lane;
    bool valid = (n < ncols);
    int ns = valid ? n : 0;

    float acc[16];
#pragma unroll
    for (int i = 0; i < 16; ++i) acc[i] = 0.f;

    const float* xrow = x + (size_t)u0 * DIN;
#pragma unroll 4
    for (int k = k0; k < k0 + 512; ++k) {
        float w = valid ? W[(size_t)k * ldw + ns] : 0.f;
#pragma unroll
        for (int i = 0; i < 16; ++i)
            acc[i] += xrow[(size_t)i * DIN + k] * w;   // x addr wave-uniform -> s_load
    }
    if (valid) {
#pragma unroll
        for (int i = 0; i < 16; ++i)
            atomicAdd(&out[(size_t)(u0 + i) * ldw + n], acc[i]);
    }
}

// -------------------------------------------------------------------------
// Kernel 2: delta = softplus(t @ W_dt + b_dt), [128,10240].
// 160 d-tiles(64) x 8 u-tiles(16) = 1280 one-wave blocks.
// t reads wave-uniform (scalar path); W_dt reads coalesced (lane = d).
// -------------------------------------------------------------------------
__global__ __launch_bounds__(64) void delta_kernel(
    const float* __restrict__ t, const float* __restrict__ Wdt,
    const float* __restrict__ b_dt, float* __restrict__ delta)
{
    int b = blockIdx.x;
    int dt_ = b % 160; int ut = b / 160;
    int d = dt_ * 64 + threadIdx.x;
    int u0 = ut * 16;

    float bias = b_dt[d];
    float acc[16];
#pragma unroll
    for (int i = 0; i < 16; ++i) acc[i] = bias;

    const float* trow = t + (size_t)u0 * RANK;
#pragma unroll 4
    for (int r = 0; r < RANK; ++r) {
        float w = Wdt[(size_t)r * DIN + d];
#pragma unroll
        for (int i = 0; i < 16; ++i)
            acc[i] += trow[(size_t)i * RANK + r] * w;  // t addr wave-uniform -> s_load
    }
#pragma unroll
    for (int i = 0; i < 16; ++i) {
        float z = acc[i];
        float sp = (z > 20.f) ? z : log1pf(__expf(z)); // softplus, threshold=20
        delta[(size_t)(u0 + i) * DIN + d] = sp;
    }
}

// -------------------------------------------------------------------------
// Kernel 3: the 42M-element state update (memory-bound, ~353 MB HBM).
// Each thread owns one float4 (4 consecutive n of one (u,d) row):
//   h_new = exp(delta*A)*h + (delta*x)*B ; y = sum_n h_new*C + D*x
// 8 lanes per (u,d); width-8 shfl_xor reduction for y. All h/h_new/A
// traffic is float4-coalesced. 10240 % 8 == 0 so no wave spans two u.
// -------------------------------------------------------------------------
__global__ __launch_bounds__(256) void ssm_kernel(
    const float* __restrict__ x, const float* __restrict__ h,
    const float* __restrict__ delta,
    const float* __restrict__ Bc, const float* __restrict__ Cc,
    const float* __restrict__ A, const float* __restrict__ Dvec,
    float* __restrict__ y, float* __restrict__ hnew)
{
    int idx4 = blockIdx.x * 256 + threadIdx.x;  // float4 index, 10485760 total
    int n4 = idx4 & 7;
    int ud = idx4 >> 3;
    int d = ud % DIN;
    int u = ud / DIN;

    float dlt = delta[ud];
    float xv  = x[ud];

    float4 hv = ((const float4*)h)[idx4];
    float4 av = ((const float4*)A)[(size_t)d * 8 + n4];
    float4 bv = ((const float4*)Bc)[u * 8 + n4];
    float4 cv = ((const float4*)Cc)[u * 8 + n4];

    float dx = dlt * xv;
    float4 hn;
    hn.x = __expf(dlt * av.x) * hv.x + dx * bv.x;
    hn.y = __expf(dlt * av.y) * hv.y + dx * bv.y;
    hn.z = __expf(dlt * av.z) * hv.z + dx * bv.z;
    hn.w = __expf(dlt * av.w) * hv.w + dx * bv.w;

    ((float4*)hnew)[idx4] = hn;

    float p = hn.x * cv.x + hn.y * cv.y + hn.z * cv.z + hn.w * cv.w;
    p += __shfl_xor(p, 4, 8);
    p += __shfl_xor(p, 2, 8);
    p += __shfl_xor(p, 1, 8);
    if (n4 == 0)
        y[ud] = p + Dvec[d] * xv;
}

// -------------------------------------------------------------------------
extern "C" void kernel_launch(void* const* d_in, const int* in_sizes, int n_in,
                              void* d_out, int out_size, void* d_ws, size_t ws_size,
                              hipStream_t stream)
{
    const float* x   = (const float*)d_in[0];
    const float* h   = (const float*)d_in[1];
    const float* Wd  = (const float*)d_in[2];
    const float* Wdt = (const float*)d_in[3];
    const float* bdt = (const float*)d_in[4];
    const float* Wb  = (const float*)d_in[5];
    const float* Wc  = (const float*)d_in[6];
    const float* A   = (const float*)d_in[7];
    const float* Dv  = (const float*)d_in[8];

    float* ws    = (float*)d_ws;
    float* t     = ws;                    // 128*320   = 40960 floats
    float* Bc    = ws + 40960;            // 128*32    = 4096
    float* Cc    = ws + 45056;            // 128*32    = 4096
    float* delta = ws + 49152;            // 128*10240 = 1310720
    // total ws use: 1359872 floats = 5.44 MB

    float* y    = (float*)d_out;          // [128,10240]
    float* hnew = y + (size_t)U_ * DIN;   // [128,10240,32]

    // zero the atomic-accumulated projections (ws is poisoned each call)
    hipMemsetAsync(d_ws, 0, 49152 * sizeof(float), stream);

    proj_kernel <<<1120, 64, 0, stream>>>(x, Wd, Wb, Wc, t, Bc, Cc);
    delta_kernel<<<1280, 64, 0, stream>>>(t, Wdt, bdt, delta);
    ssm_kernel  <<<40960, 256, 0, stream>>>(x, h, delta, Bc, Cc, A, Dv, y, hnew);
}

// Round 2
// 481.743 us; speedup vs baseline: 1.0055x; 1.0055x over previous
//
#include <hip/hip_runtime.h>

#define U_    128
#define DIN   10240
#define RANK  320
#define NS    32
#define NTOT  384          // 320 (t) + 32 (B) + 32 (C)
#define KC    32           // k-split count in gemmA
#define KCH   (DIN / KC)   // 320 k per chunk

// -------------------------------------------------------------------------
// Kernel 0: transpose x[128,10240] -> xT[10240,128] so GEMM vector loads
// along u are coalesced. 10.5 MB traffic, ~2 us.
// -------------------------------------------------------------------------
__global__ __launch_bounds__(256) void transpose_kernel(
    const float* __restrict__ x, float* __restrict__ xT)
{
    __shared__ float tile[32][33];
    int kb = blockIdx.x * 32, ub = blockIdx.y * 32;
    int tx = threadIdx.x, ty = threadIdx.y;      // (32, 8)
#pragma unroll
    for (int i = 0; i < 32; i += 8)
        tile[ty + i][tx] = x[(size_t)(ub + ty + i) * DIN + kb + tx];
    __syncthreads();
#pragma unroll
    for (int i = 0; i < 32; i += 8)
        xT[(size_t)(kb + ty + i) * U_ + ub + tx] = tile[tx][ty + i];
}

// -------------------------------------------------------------------------
// Kernel 1: gemmA — partial[kc][n][u] = sum_{k in chunk} xT[k,u] * W[k,n]
// for n in [0,384) = [t cols | B cols | C cols].
// lane = u (coalesced xT loads); W addresses wave-uniform & contiguous
// (n-tile of 32 = 128 B slice per k row -> s_load path, scalar-cache hits).
// 768 one-wave blocks = 75% SIMD fill; 32 fma per k-iter of pure ILP.
// -------------------------------------------------------------------------
__global__ __launch_bounds__(64) void gemmA_kernel(
    const float* __restrict__ xT,
    const float* __restrict__ Wd, const float* __restrict__ Wb,
    const float* __restrict__ Wc,
    float* __restrict__ partial)
{
    int b  = blockIdx.x;          // 2 uh * 12 nt * 32 kc = 768
    int uh = b & 1;
    int nt = (b >> 1) % 12;
    int kc = b / 24;
    int u  = uh * 64 + threadIdx.x;
    int n0 = nt * 32;

    const float* W; int ldw, c0;
    if (nt < 10)       { W = Wd; ldw = RANK; c0 = n0; }
    else if (nt == 10) { W = Wb; ldw = NS;   c0 = 0;  }
    else               { W = Wc; ldw = NS;   c0 = 0;  }

    float acc[32];
#pragma unroll
    for (int j = 0; j < 32; ++j) acc[j] = 0.f;

    int k0 = kc * KCH;
    const float* Wp = W  + (size_t)k0 * ldw + c0;
    const float* xp = xT + (size_t)k0 * U_ + u;

#pragma unroll 2
    for (int k = 0; k < KCH; ++k) {
        float xv = xp[(size_t)k * U_];           // coalesced 256 B v_load
#pragma unroll
        for (int j = 0; j < 32; ++j)
            acc[j] += xv * Wp[(size_t)k * ldw + j];  // wave-uniform -> s_load
    }

    float* out = partial + (size_t)kc * (NTOT * U_) + (size_t)n0 * U_ + u;
#pragma unroll
    for (int j = 0; j < 32; ++j)
        out[(size_t)j * U_] = acc[j];            // coalesced, no atomics
}

// -------------------------------------------------------------------------
// Kernel 2: reduce 32 k-chunk partials -> tT[320,128], B[128,32], C[128,32].
// 12.6 MB read, 0.2 MB write.
// -------------------------------------------------------------------------
__global__ __launch_bounds__(256) void reduce_kernel(
    const float* __restrict__ partial, float* __restrict__ tT,
    float* __restrict__ Bc, float* __restrict__ Cc)
{
    int e = blockIdx.x * 256 + threadIdx.x;      // 0..49151
    float s = 0.f;
#pragma unroll 8
    for (int kc = 0; kc < KC; ++kc)
        s += partial[(size_t)kc * (NTOT * U_) + e];
    int n = e >> 7, u = e & 127;                 // e = n*128 + u
    if (n < RANK)            tT[e] = s;
    else if (n < RANK + NS)  Bc[u * NS + (n - RANK)] = s;
    else                     Cc[u * NS + (n - RANK - NS)] = s;
}

// -------------------------------------------------------------------------
// Kernel 3: delta = softplus(t @ W_dt + b_dt).
// lane = d: W_dt[r,d] coalesced; tT[r,u] wave-uniform contiguous -> s_load.
// 160 d-tiles x 4 u-tiles = 640 waves; W_dt re-read 4x = 52 MB (L3-hit).
// -------------------------------------------------------------------------
__global__ __launch_bounds__(64) void delta_kernel(
    const float* __restrict__ tT, const float* __restrict__ Wdt,
    const float* __restrict__ b_dt, float* __restrict__ delta)
{
    int b  = blockIdx.x;
    int dt_ = b % 160, ut = b / 160;
    int d  = dt_ * 64 + threadIdx.x;
    int u0 = ut * 32;

    float bias = b_dt[d];
    float acc[32];
#pragma unroll
    for (int i = 0; i < 32; ++i) acc[i] = bias;

#pragma unroll 2
    for (int r = 0; r < RANK; ++r) {
        float w = Wdt[(size_t)r * DIN + d];      // coalesced v_load
        const float* tp = tT + r * U_ + u0;
#pragma unroll
        for (int i = 0; i < 32; ++i)
            acc[i] += w * tp[i];                 // wave-uniform -> s_load
    }
#pragma unroll
    for (int i = 0; i < 32; ++i) {
        float z = acc[i];
        float sp = (z > 20.f) ? z : log1pf(__expf(z));
        delta[(size_t)(u0 + i) * DIN + d] = sp;
    }
}

// -------------------------------------------------------------------------
// Kernel 4: state update (memory-bound, ~353 MB HBM). Unchanged from R1.
// -------------------------------------------------------------------------
__global__ __launch_bounds__(256) void ssm_kernel(
    const float* __restrict__ x, const float* __restrict__ h,
    const float* __restrict__ delta,
    const float* __restrict__ Bc, const float* __restrict__ Cc,
    const float* __restrict__ A, const float* __restrict__ Dvec,
    float* __restrict__ y, float* __restrict__ hnew)
{
    int idx4 = blockIdx.x * 256 + threadIdx.x;   // float4 index
    int n4 = idx4 & 7;
    int ud = idx4 >> 3;
    int d = ud % DIN;
    int u = ud / DIN;

    float dlt = delta[ud];
    float xv  = x[ud];

    float4 hv = ((const float4*)h)[idx4];
    float4 av = ((const float4*)A)[(size_t)d * 8 + n4];
    float4 bv = ((const float4*)Bc)[u * 8 + n4];
    float4 cv = ((const float4*)Cc)[u * 8 + n4];

    float dx = dlt * xv;
    float4 hn;
    hn.x = __expf(dlt * av.x) * hv.x + dx * bv.x;
    hn.y = __expf(dlt * av.y) * hv.y + dx * bv.y;
    hn.z = __expf(dlt * av.z) * hv.z + dx * bv.z;
    hn.w = __expf(dlt * av.w) * hv.w + dx * bv.w;

    ((float4*)hnew)[idx4] = hn;

    float p = hn.x * cv.x + hn.y * cv.y + hn.z * cv.z + hn.w * cv.w;
    p += __shfl_xor(p, 4, 8);
    p += __shfl_xor(p, 2, 8);
    p += __shfl_xor(p, 1, 8);
    if (n4 == 0)
        y[ud] = p + Dvec[d] * xv;
}

// -------------------------------------------------------------------------
extern "C" void kernel_launch(void* const* d_in, const int* in_sizes, int n_in,
                              void* d_out, int out_size, void* d_ws, size_t ws_size,
                              hipStream_t stream)
{
    const float* x   = (const float*)d_in[0];
    const float* h   = (const float*)d_in[1];
    const float* Wd  = (const float*)d_in[2];
    const float* Wdt = (const float*)d_in[3];
    const float* bdt = (const float*)d_in[4];
    const float* Wb  = (const float*)d_in[5];
    const float* Wc  = (const float*)d_in[6];
    const float* A   = (const float*)d_in[7];
    const float* Dv  = (const float*)d_in[8];

    float* ws      = (float*)d_ws;
    float* xT      = ws;                       // 10240*128       = 1310720
    float* partial = ws + 1310720;             // 32*384*128      = 1572864
    float* delta   = partial;                  // ALIAS: partial dead after reduce
    float* tT      = ws + 1310720 + 1572864;   // 320*128         = 40960
    float* Bc      = tT + 40960;               // 128*32          = 4096
    float* Cc      = Bc + 4096;                // 128*32          = 4096
    // total ws use: 2932736 floats = 11.2 MB

    float* y    = (float*)d_out;               // [128,10240]
    float* hnew = y + (size_t)U_ * DIN;        // [128,10240,32]

    dim3 tb(32, 8);
    transpose_kernel<<<dim3(DIN / 32, U_ / 32), tb, 0, stream>>>(x, xT);
    gemmA_kernel    <<<768, 64, 0, stream>>>(xT, Wd, Wb, Wc, partial);
    reduce_kernel   <<<192, 256, 0, stream>>>(partial, tT, Bc, Cc);
    delta_kernel    <<<640, 64, 0, stream>>>(tT, Wdt, bdt, delta);
    ssm_kernel      <<<40960, 256, 0, stream>>>(x, h, delta, Bc, Cc, A, Dv, y, hnew);
}